// Round 1
// baseline (8115.155 us; speedup 1.0000x reference)
//
#include <hip/hip_runtime.h>
#include <cstdint>
#include <cstddef>

// Problem constants (B,T,D,H,L = 16,4096,256,256,2)
#define T_SEQ 4096
#define BATCH 16
#define HID   256
#define GATES 1024   // 4*H, torch gate order i,f,g,o
#define DIN   256

typedef _Float16 h2 __attribute__((ext_vector_type(2)));
typedef _Float16 h8 __attribute__((ext_vector_type(8)));
typedef float    f4 __attribute__((ext_vector_type(4)));

// K2 weight split: per gate-row, k in [0,200) lives in VGPRs (100 x half2),
// k in [200,256) lives in LDS (28 dwords/row, stride 28 dw = 112B: 16B-aligned,
// 28 mod 8 == 4 -> b128 reads spread uniformly over all 32 banks).
#define NREG 100
#define LDSW_DW 28
#define LDSW_BYTES (GATES * LDSW_DW * 4)         // 114688
#define HBUF_BYTES (2 * HID * 2)                 // 1024  (double-buffered f16 h)
#define GBUF_BYTES (2 * 2 * HID * 4)             // 4096  (f,o preact exchange)
#define K2_LDS (LDSW_BYTES + HBUF_BYTES + GBUF_BYTES + 32)   // 119840

__device__ __forceinline__ float dot2f(h2 a, h2 b, float c) {
#if __has_builtin(__builtin_amdgcn_fdot2)
  return __builtin_amdgcn_fdot2(a, b, c, false);
#else
  return c + (float)a[0] * (float)b[0] + (float)a[1] * (float)b[1];
#endif
}

__device__ __forceinline__ float sigmf_(float x) {
  x = fminf(fmaxf(x, -30.0f), 30.0f);
  return 1.0f / (1.0f + __expf(-x));
}
__device__ __forceinline__ float tanhf_(float x) {
  x = fminf(fmaxf(x, -15.0f), 15.0f);
  const float e = __expf(2.0f * x);
  return (e - 1.0f) / (e + 1.0f);
}

// ---------------------------------------------------------------------------
// K1: xp[m][g] = sum_k x[m][k]*Wih[g][k] + bih[g] + bhh[g], stored f16.
// 64x64 tile per 256-thread WG; wave w does rows [16w,16w+16) x 64 cols.
// MFMA f32_16x16x32_f16; A/B frag: lane l -> row/col = l&15, k = 8*(l>>4)+e.
// D frag: col = l&15, row = 4*(l>>4)+r  (guide-verified layout).
// ---------------------------------------------------------------------------
__global__ __launch_bounds__(256) void k1_xproj(
    const float* __restrict__ x, const float* __restrict__ Wih,
    const float* __restrict__ bih, const float* __restrict__ bhh,
    _Float16* __restrict__ xp) {
  const int bid = blockIdx.x;
  const int mt = bid >> 4;          // 1024 M-tiles
  const int nt = bid & 15;          // 16 N-tiles
  const int tid = threadIdx.x;
  const int wv = tid >> 6;
  const int l  = tid & 63;
  const int lr = l & 15;
  const int lq = l >> 4;

  const int arow = mt * 64 + wv * 16 + lr;
  const float* xr = x + (size_t)arow * DIN;

  f4 acc[4] = {};
  #pragma unroll
  for (int ks = 0; ks < 8; ++ks) {
    const int k0 = ks * 32 + lq * 8;
    const float4 a1 = *(const float4*)(xr + k0);
    const float4 a2 = *(const float4*)(xr + k0 + 4);
    const h8 af = { (_Float16)a1.x, (_Float16)a1.y, (_Float16)a1.z, (_Float16)a1.w,
                    (_Float16)a2.x, (_Float16)a2.y, (_Float16)a2.z, (_Float16)a2.w };
    #pragma unroll
    for (int n = 0; n < 4; ++n) {
      const int col = nt * 64 + n * 16 + lr;
      const float* wr = Wih + (size_t)col * DIN + k0;
      const float4 b1 = *(const float4*)wr;
      const float4 b2 = *(const float4*)(wr + 4);
      const h8 bf = { (_Float16)b1.x, (_Float16)b1.y, (_Float16)b1.z, (_Float16)b1.w,
                      (_Float16)b2.x, (_Float16)b2.y, (_Float16)b2.z, (_Float16)b2.w };
      acc[n] = __builtin_amdgcn_mfma_f32_16x16x32_f16(af, bf, acc[n], 0, 0, 0);
    }
  }
  #pragma unroll
  for (int n = 0; n < 4; ++n) {
    const int col = nt * 64 + n * 16 + lr;
    const float bias = bih[col] + bhh[col];
    #pragma unroll
    for (int r = 0; r < 4; ++r) {
      const int row = mt * 64 + wv * 16 + lq * 4 + r;
      xp[(size_t)row * GATES + col] = (_Float16)(acc[n][r] + bias);
    }
  }
}

// ---------------------------------------------------------------------------
// K2: sequential LSTM, one WG per batch (16 WGs, no cross-WG sync).
// 512 threads: thread tid owns gate rows r0=tid, r1=tid+512.
//   tid<256  -> rows (i_j, g_j), owns hidden unit j = tid: c/h state, inc, out
//   tid>=256 -> rows (f_j, o_j), exchanges preacts via LDS
// Weights: 200 f16/row in VGPRs + 56 f16/row in LDS. h broadcast via LDS f16.
// Fused epilogue part A: out = 2h - w*fw + inc*(fw-bw), tot saved for K3.
// ---------------------------------------------------------------------------
__global__ __launch_bounds__(512, 2) void k2_lstm(
    const _Float16* __restrict__ xp, const float* __restrict__ Whh,
    const float* __restrict__ Wlin, const float* __restrict__ blin,
    const float* __restrict__ fw, const float* __restrict__ bw,
    float* __restrict__ out, float* __restrict__ tot) {
  extern __shared__ __align__(16) char smem[];
  h2*       ldsW  = (h2*)smem;                                   // [1024][28] dw
  _Float16* hbufP = (_Float16*)(smem + LDSW_BYTES);              // [2][256]
  float*    gbufP = (float*)(smem + LDSW_BYTES + HBUF_BYTES);    // [2][2][256]
  float*    pbufP = (float*)(smem + LDSW_BYTES + HBUF_BYTES + GBUF_BYTES); // [2][4]

  const int b   = blockIdx.x;
  const int tid = threadIdx.x;
  const int r0  = tid;
  const int r1  = tid + 512;
  const bool lower = (tid < 256);
  const int j = tid & 255;

  if (tid < 256) { hbufP[tid] = (_Float16)0.0f; hbufP[256 + tid] = (_Float16)0.0f; }

  // Register-resident weights, k in [0,200)
  h2 wA[NREG], wB[NREG];
  {
    const float2* w0p = (const float2*)(Whh + (size_t)r0 * HID);
    const float2* w1p = (const float2*)(Whh + (size_t)r1 * HID);
    #pragma unroll
    for (int i = 0; i < NREG; ++i) {
      const float2 f0 = w0p[i]; const float2 f1 = w1p[i];
      wA[i] = (h2){ (_Float16)f0.x, (_Float16)f0.y };
      wB[i] = (h2){ (_Float16)f1.x, (_Float16)f1.y };
    }
  }
  // LDS-resident weights, k in [200,256)
  {
    const float2* wr0 = (const float2*)(Whh + (size_t)r0 * HID + 2 * NREG);
    const float2* wr1 = (const float2*)(Whh + (size_t)r1 * HID + 2 * NREG);
    #pragma unroll
    for (int i = 0; i < LDSW_DW; ++i) {
      const float2 f0 = wr0[i]; const float2 f1 = wr1[i];
      ldsW[(size_t)r0 * LDSW_DW + i] = (h2){ (_Float16)f0.x, (_Float16)f0.y };
      ldsW[(size_t)r1 * LDSW_DW + i] = (h2){ (_Float16)f1.x, (_Float16)f1.y };
    }
  }

  float fwj = 0.f, dfw = 0.f, dwj = 0.f, db = 0.f;
  if (lower) {
    fwj = fw[j];
    const float bwj = bw[j];
    dfw = fwj - bwj;
    dwj = Wlin[HID + j] - Wlin[j];   // logit1 - logit0 weight
    db  = blin[1] - blin[0];
  }

  float creg = 0.0f, incj = 0.0f;

  const _Float16* xpb = xp + (size_t)b * T_SEQ * GATES;
  float* outb = out + (size_t)b * T_SEQ * HID;

  // xp prefetch pipeline, depth 2 (HBM latency ~900ns vs ~600ns step)
  _Float16 x0a = xpb[r0],          x0b = xpb[r1];
  _Float16 x1a = xpb[GATES + r0],  x1b = xpb[GATES + r1];

  __syncthreads();

  for (int t = 0; t < T_SEQ; ++t) {
    const int pt = t & 1;
    const int pr = pt ^ 1;

    int tp = t + 2; if (tp > T_SEQ - 1) tp = T_SEQ - 1;
    const _Float16 x2a = xpb[(size_t)tp * GATES + r0];
    const _Float16 x2b = xpb[(size_t)tp * GATES + r1];

    float a0 = (float)x0a;   // gate preact accumulators (bias already in xp)
    float a1 = (float)x0b;

    const h8* hb8 = (const h8*)(hbufP + pr * HID);
    #pragma unroll
    for (int c = 0; c < 25; ++c) {
      const h8 hv = hb8[c];   // uniform broadcast read of h[8c..8c+7]
      const h2 hp0 = { hv[0], hv[1] }, hp1 = { hv[2], hv[3] },
               hp2 = { hv[4], hv[5] }, hp3 = { hv[6], hv[7] };
      a0 = dot2f(wA[4*c+0], hp0, a0);
      a0 = dot2f(wA[4*c+1], hp1, a0);
      a0 = dot2f(wA[4*c+2], hp2, a0);
      a0 = dot2f(wA[4*c+3], hp3, a0);
      a1 = dot2f(wB[4*c+0], hp0, a1);
      a1 = dot2f(wB[4*c+1], hp1, a1);
      a1 = dot2f(wB[4*c+2], hp2, a1);
      a1 = dot2f(wB[4*c+3], hp3, a1);
    }
    const h8* w8 = (const h8*)ldsW;
    #pragma unroll
    for (int c = 0; c < 7; ++c) {
      const h8 hv = hb8[25 + c];
      const h8 u0 = w8[(size_t)r0 * 7 + c];
      const h8 u1 = w8[(size_t)r1 * 7 + c];
      const h2 hp0 = { hv[0], hv[1] }, hp1 = { hv[2], hv[3] },
               hp2 = { hv[4], hv[5] }, hp3 = { hv[6], hv[7] };
      a0 = dot2f((h2){u0[0], u0[1]}, hp0, a0);
      a0 = dot2f((h2){u0[2], u0[3]}, hp1, a0);
      a0 = dot2f((h2){u0[4], u0[5]}, hp2, a0);
      a0 = dot2f((h2){u0[6], u0[7]}, hp3, a0);
      a1 = dot2f((h2){u1[0], u1[1]}, hp0, a1);
      a1 = dot2f((h2){u1[2], u1[3]}, hp1, a1);
      a1 = dot2f((h2){u1[4], u1[5]}, hp2, a1);
      a1 = dot2f((h2){u1[6], u1[7]}, hp3, a1);
    }

    if (!lower) {
      gbufP[pt * 512 + j]       = a0;   // f preact
      gbufP[pt * 512 + 256 + j] = a1;   // o preact
    }
    __syncthreads();   // B1: f,o visible to lower threads

    float hval = 0.0f;
    if (lower) {
      const float ig = sigmf_(a0);
      const float gg = tanhf_(a1);
      const float fg = sigmf_(gbufP[pt * 512 + j]);
      const float og = sigmf_(gbufP[pt * 512 + 256 + j]);
      creg = fg * creg + ig * gg;
      hval = og * tanhf_(creg);
      hbufP[pt * HID + j] = (_Float16)hval;
      // logit-diff partial for argmax gate
      float p = hval * dwj;
      #pragma unroll
      for (int off = 32; off >= 1; off >>= 1) p += __shfl_xor(p, off);
      if ((tid & 63) == 0) pbufP[pt * 4 + (tid >> 6)] = p;
    }
    __syncthreads();   // B2: h_t + logit partials visible

    if (lower) {
      const float d = pbufP[pt*4+0] + pbufP[pt*4+1] + pbufP[pt*4+2] + pbufP[pt*4+3] + db;
      const float gf = (d > 0.0f) ? 1.0f : 0.0f;   // argmax (ties -> 0)
      const float wvv = gf * hval;
      incj += wvv;
      outb[(size_t)t * HID + j] = 2.0f * hval - wvv * fwj + incj * dfw;
    }

    x0a = x1a; x0b = x1b; x1a = x2a; x1b = x2b;
  }

  if (lower) tot[b * HID + j] = incj;
}

// ---------------------------------------------------------------------------
// K3: out += tot[b,j] * bw[j]   (suffix total term), vectorized float4
// ---------------------------------------------------------------------------
__global__ __launch_bounds__(256) void k3_add(
    float* __restrict__ out, const float* __restrict__ tot,
    const float* __restrict__ bw) {
  const int gid = blockIdx.x * 256 + threadIdx.x;        // 4,194,304 groups
  const size_t e = (size_t)gid * 4;
  const int b  = (int)(e >> 20);                         // 4096*256 = 2^20 per batch
  const int jb = ((int)(e & 255)) >> 2;
  float4 v = ((float4*)out)[gid];
  const float4 tt = ((const float4*)tot)[b * 64 + jb];
  const float4 bb = ((const float4*)bw)[jb];
  v.x += tt.x * bb.x; v.y += tt.y * bb.y;
  v.z += tt.z * bb.z; v.w += tt.w * bb.w;
  ((float4*)out)[gid] = v;
}

extern "C" void kernel_launch(void* const* d_in, const int* in_sizes, int n_in,
                              void* d_out, int out_size, void* d_ws, size_t ws_size,
                              hipStream_t stream) {
  const float* x    = (const float*)d_in[0];
  const float* Wih  = (const float*)d_in[1];
  const float* Whh  = (const float*)d_in[2];
  const float* bih  = (const float*)d_in[3];
  const float* bhh  = (const float*)d_in[4];
  const float* Wlin = (const float*)d_in[5];
  const float* blin = (const float*)d_in[6];
  const float* fw   = (const float*)d_in[7];
  const float* bw   = (const float*)d_in[8];
  float* out = (float*)d_out;

  // Workspace: xp f16 [65536][1024] = 128 MiB, then tot f32 [16][256]
  _Float16* xp = (_Float16*)d_ws;
  float* tot = (float*)((char*)d_ws + (size_t)BATCH * T_SEQ * GATES * 2);

  k1_xproj<<<dim3(16384), dim3(256), 0, stream>>>(x, Wih, bih, bhh, xp);

  (void)hipFuncSetAttribute((const void*)k2_lstm,
                            hipFuncAttributeMaxDynamicSharedMemorySize, K2_LDS);
  k2_lstm<<<dim3(BATCH), dim3(512), K2_LDS, stream>>>(xp, Whh, Wlin, blin, fw, bw, out, tot);

  k3_add<<<dim3(16384), dim3(256), 0, stream>>>(out, tot, bw);
}